// Round 7
// baseline (277.753 us; speedup 1.0000x reference)
//
#include <hip/hip_runtime.h>
#include <math.h>

// WaveletLayerND: fused mexican-hat wavelet + grouped 3x3 conv (kernel 1),
// then 1x1 channel mix (kernel 2). B=4, O=I=32, H=W=128, fp32 throughout.
//
// Round 7: TLP push. Diagnosis r6: VALUBusy is CU-level; per-SIMD issue is
// ~17% -> latency-bound with ~2 resident waves/SIMD (VGPR=76 -> 4-wave cap).
// Fix: 1 input channel per inner iteration (not 2) shrinks the live set so
// the (256,4) cap (=64 VGPRs on this hipcc, r4 evidence) fits WITHOUT spill
// -> 8 waves/SIMD HW cap. acc stays 8x v2f = 16 VGPRs (RSTRIP=8, halo 1.25x).
// Spill tripwire: steady-state WRITE_SIZE must stay ~8.2 MB.

#define RSTRIP 8   // output rows per wave

typedef float v2f __attribute__((ext_vector_type(2)));

static __device__ __forceinline__ v2f vfma(float w, v2f a, v2f c) {
  return __builtin_elementwise_fma(a, (v2f){w, w}, c);
}
static __device__ __forceinline__ float bperm(int addr, float v) {
  return __int_as_float(__builtin_amdgcn_ds_bpermute(addr, __float_as_int(v)));
}

__global__ __launch_bounds__(256, 4) void wavelet_grouped_conv(
    const float* __restrict__ x,      // (B, I, H, W)
    const float* __restrict__ scale,  // (O*I)
    const float* __restrict__ trans,  // (O*I)
    const float* __restrict__ wconv,  // (O, I, 3, 3)
    float* __restrict__ y,            // (B, O, H, W) workspace
    float mhc)
{
  const int tid   = threadIdx.x;
  const int lane  = tid & 63;
  const int iq    = tid >> 6;          // 0..3: which i-quarter this wave owns
  const int strip = blockIdx.x;        // 0..15
  const int o     = blockIdx.y;        // 0..31
  const int b     = blockIdx.z;        // 0..3
  const int r0    = strip * RSTRIP;
  const int c0    = lane << 1;         // this thread's two columns

  // hoisted bpermute byte-addresses: lane-1 and lane+1 (mod 64)
  const int a_up = ((lane + 63) & 63) << 2;
  const int a_dn = ((lane +  1) & 63) << 2;

  const float NHL2E = -0.72134752044448170f; // -0.5 * log2(e)

  v2f acc[RSTRIP];
#pragma unroll
  for (int r = 0; r < RSTRIP; ++r) acc[r] = (v2f){0.f, 0.f};

  const float* xb = x + (size_t)b * 32 * 128 * 128;

#pragma unroll 1
  for (int ii = 0; ii < 8; ++ii) {
    const int i0 = iq * 8 + ii;                 // wave-uniform
    const int oi = __builtin_amdgcn_readfirstlane(o * 32 + i0);
    const float rs  = 1.0f / scale[oi];
    const float trs = trans[oi] * rs;
    const float* wp = wconv + oi * 9;
    const float w00 = wp[0], w01 = wp[1], w02 = wp[2];
    const float w10 = wp[3], w11 = wp[4], w12 = wp[5];
    const float w20 = wp[6], w21 = wp[7], w22 = wp[8];
    const float* xi = xb + (size_t)i0 * 128 * 128;

#pragma unroll
    for (int j = 0; j < RSTRIP + 2; ++j) {
      const int ir = r0 + j - 1;           // input row (wave-uniform)
      if (ir >= 0 && ir < 128) {           // outside rows: wt = 0 (zero pad)
        const v2f xv = *(const v2f*)(xi + ir * 128 + c0);
        // psi((x-t)/s) = MH_C*(u-1)*exp(-u/2), u = sx^2  — packed
        const v2f sx = __builtin_elementwise_fma(xv, (v2f){rs, rs},
                                                 (v2f){-trs, -trs});
        const v2f u  = sx * sx;
        const v2f ar = u * (v2f){NHL2E, NHL2E};
        v2f e;
        e.x = __builtin_amdgcn_exp2f(ar.x);
        e.y = __builtin_amdgcn_exp2f(ar.y);
        const v2f p = __builtin_elementwise_fma(u, (v2f){mhc, mhc},
                                                (v2f){-mhc, -mhc}) * e;
        // halo: pl = psi(c0-1) from lane-1, pr = psi(c0+2) from lane+1
        float pl = bperm(a_up, p.y);
        float pr = bperm(a_dn, p.x);
        if (lane == 0)  pl = 0.f;
        if (lane == 63) pr = 0.f;
        const v2f L = (v2f){pl, p.x};   // {psi(c0-1), psi(c0)}
        const v2f R = (v2f){p.y, pr};   // {psi(c0+1), psi(c0+2)}

        // acc.x += w0*pl + w1*p0 + w2*p1 ; acc.y += w0*p0 + w1*p1 + w2*pr
        // input row ir feeds output rows ir+1 (kh=0), ir (kh=1), ir-1 (kh=2)
        if (j <= RSTRIP - 1) {
          acc[j] = vfma(w00, L, acc[j]);
          acc[j] = vfma(w01, p, acc[j]);
          acc[j] = vfma(w02, R, acc[j]);
        }
        if (j >= 1 && j <= RSTRIP) {
          acc[j-1] = vfma(w10, L, acc[j-1]);
          acc[j-1] = vfma(w11, p, acc[j-1]);
          acc[j-1] = vfma(w12, R, acc[j-1]);
        }
        if (j >= 2) {
          acc[j-2] = vfma(w20, L, acc[j-2]);
          acc[j-2] = vfma(w21, p, acc[j-2]);
          acc[j-2] = vfma(w22, R, acc[j-2]);
        }
      }
    }
  }

  // reduce the four i-quarters through LDS (lane-major; b64 2-way is free)
  __shared__ v2f red[3][RSTRIP][64];   // 12 KB
  if (iq != 0) {
#pragma unroll
    for (int r = 0; r < RSTRIP; ++r) red[iq - 1][r][lane] = acc[r];
  }
  __syncthreads();
  if (iq == 0) {
    float* yb = y + (((size_t)b * 32 + o) * 128 + r0) * 128 + c0;
#pragma unroll
    for (int r = 0; r < RSTRIP; ++r) {
      const v2f v = acc[r] + red[0][r][lane] + red[1][r][lane] + red[2][r][lane];
      *(v2f*)(yb + (size_t)r * 128) = v;
    }
  }
}

__global__ __launch_bounds__(256) void mix1x1(
    const float* __restrict__ y,    // (B, O, H*W)
    const float* __restrict__ fw,   // (O_out, O_in)
    float* __restrict__ out)        // (B, O, H*W)
{
  const int px = blockIdx.x * 256 + threadIdx.x;  // 0..16383
  const int b  = blockIdx.y;
  const float* yb = y + (size_t)b * 32 * 16384 + px;
  float v[32];
#pragma unroll
  for (int o = 0; o < 32; ++o) v[o] = yb[(size_t)o * 16384];
  float* ob = out + (size_t)b * 32 * 16384 + px;
#pragma unroll
  for (int p = 0; p < 32; ++p) {
    float a = 0.f;
#pragma unroll
    for (int o = 0; o < 32; ++o) a = fmaf(fw[p * 32 + o], v[o], a);
    ob[(size_t)p * 16384] = a;
  }
}

extern "C" void kernel_launch(void* const* d_in, const int* in_sizes, int n_in,
                              void* d_out, int out_size, void* d_ws, size_t ws_size,
                              hipStream_t stream) {
  const float* x     = (const float*)d_in[0];
  const float* scale = (const float*)d_in[1];
  const float* trans = (const float*)d_in[2];
  const float* wconv = (const float*)d_in[3];
  const float* fw    = (const float*)d_in[4];
  float* out = (float*)d_out;
  float* y   = (float*)d_ws;   // 4*32*128*128 floats = 8.39 MB

  const float mhc = (float)(2.0 / (sqrt(3.0) * pow(M_PI, 0.25)));

  dim3 g1(128 / RSTRIP, 32, 4);  // (strips, o, b) = 2048 blocks x 256 thr
  wavelet_grouped_conv<<<g1, 256, 0, stream>>>(x, scale, trans, wconv, y, mhc);

  dim3 g2(16384 / 256, 4);       // (pixel tiles, b)
  mix1x1<<<g2, 256, 0, stream>>>(y, fw, out);
}

// Round 8
// 49.899 us; speedup vs baseline: 5.5663x; 5.5663x over previous
//
#include <hip/hip_runtime.h>
#include <math.h>

// WaveletLayerND: fused mexican-hat wavelet + grouped 3x3 conv (kernel 1),
// then 1x1 channel mix (kernel 2). B=4, O=I=32, H=W=128, fp32 throughout.
//
// Round 8: latency-structure rewrite. r7 lesson: never cap VGPR below the
// natural footprint (spill -> scratch HBM traffic). r1-r6 lesson: the old
// branchy j-body exposed ~450 cy of L2+bperm latency per step (loads issued
// and immediately waited inside each `if(ir valid)` block).
// New inner loop: straight-line, 3-row rolling psi window, row validity via
// multiply-by-0/1 (exact zero-padding), row address clamped (always in-image),
// explicit lookahead-2 on x loads so vmcnt waits are covered by ~2 iterations
// of independent VALU work. 1 channel/iter (unroll 1) keeps VGPR near 64.

#define RSTRIP 8   // output rows per wave

typedef float v2f __attribute__((ext_vector_type(2)));

static __device__ __forceinline__ v2f vfma(float w, v2f a, v2f c) {
  return __builtin_elementwise_fma(a, (v2f){w, w}, c);
}
static __device__ __forceinline__ float bperm(int addr, float v) {
  return __int_as_float(__builtin_amdgcn_ds_bpermute(addr, __float_as_int(v)));
}

__global__ __launch_bounds__(256) void wavelet_grouped_conv(
    const float* __restrict__ x,      // (B, I, H, W)
    const float* __restrict__ scale,  // (O*I)
    const float* __restrict__ trans,  // (O*I)
    const float* __restrict__ wconv,  // (O, I, 3, 3)
    float* __restrict__ y,            // (B, O, H, W) workspace
    float mhc)
{
  const int tid   = threadIdx.x;
  const int lane  = tid & 63;
  const int iq    = tid >> 6;          // 0..3: which i-quarter this wave owns
  const int strip = blockIdx.x;        // 0..15
  const int o     = blockIdx.y;        // 0..31
  const int b     = blockIdx.z;        // 0..3
  const int r0    = strip * RSTRIP;
  const int c0    = lane << 1;         // this thread's two columns

  // hoisted bpermute byte-addresses: lane-1 and lane+1 (mod 64)
  const int a_up = ((lane + 63) & 63) << 2;
  const int a_dn = ((lane +  1) & 63) << 2;
  const bool lane0  = (lane == 0);
  const bool lane63 = (lane == 63);

  // row-validity factors (only the top halo row and the bottom rows can be
  // outside the image; multiplying psi by 0 == the conv's zero padding)
  const float rvm1 = (r0 > 0)        ? 1.f : 0.f;   // row r0-1
  const float rv8  = (r0 + 8 < 128)  ? 1.f : 0.f;   // row r0+8

  const float NHL2E = -0.72134752044448170f; // -0.5 * log2(e)

  v2f acc[RSTRIP];
#pragma unroll
  for (int r = 0; r < RSTRIP; ++r) acc[r] = (v2f){0.f, 0.f};

  const float* xb = x + (size_t)b * 32 * 128 * 128;

#pragma unroll 1
  for (int ii = 0; ii < 8; ++ii) {
    const int i0 = iq * 8 + ii;                 // wave-uniform
    const int oi = __builtin_amdgcn_readfirstlane(o * 32 + i0);
    const float rs  = 1.0f / scale[oi];
    const float trs = trans[oi] * rs;
    const float* wp = wconv + oi * 9;
    const float w00 = wp[0], w01 = wp[1], w02 = wp[2];
    const float w10 = wp[3], w11 = wp[4], w12 = wp[5];
    const float w20 = wp[6], w21 = wp[7], w22 = wp[8];
    const float* base = xb + (size_t)i0 * 128 * 128 + c0;  // per-thread col base

    // clamped row load: always a legal in-image address; invalid rows are
    // zeroed at the psi stage via rv
#define LDROW(r) (*(const v2f*)(base + (size_t)(min(max((r), 0), 127)) * 128))

    // psi + halo for one row: L={psi(c0-1),psi(c0)}, C={psi(c0),psi(c0+1)},
    // R={psi(c0+1),psi(c0+2)}
#define MK(xv, rv, L, C, R) {                                        \
      const v2f sx_ = __builtin_elementwise_fma((xv), (v2f){rs, rs}, \
                                                (v2f){-trs, -trs});  \
      const v2f u_  = sx_ * sx_;                                     \
      v2f e_;                                                        \
      e_.x = __builtin_amdgcn_exp2f(u_.x * NHL2E);                   \
      e_.y = __builtin_amdgcn_exp2f(u_.y * NHL2E);                   \
      const v2f p_ = __builtin_elementwise_fma(u_, (v2f){mhc, mhc},  \
                      (v2f){-mhc, -mhc}) * e_ * (v2f){(rv), (rv)};   \
      float pl_ = bperm(a_up, p_.y);                                 \
      float pr_ = bperm(a_dn, p_.x);                                 \
      if (lane0)  pl_ = 0.f;                                         \
      if (lane63) pr_ = 0.f;                                         \
      (L) = (v2f){pl_, p_.x}; (C) = p_; (R) = (v2f){p_.y, pr_};      \
    }

    v2f Lm, Cm, Rm, Lc, Cc, Rc;
    v2f xC, xD;
    {
      const v2f xA = LDROW(r0 - 1);
      const v2f xB = LDROW(r0);
      xC = LDROW(r0 + 1);
      xD = LDROW(r0 + 2);
      MK(xA, rvm1, Lm, Cm, Rm)
      MK(xB, 1.f,  Lc, Cc, Rc)
    }

#pragma unroll
    for (int r = 0; r < RSTRIP; ++r) {
      const v2f xE = LDROW(r0 + r + 3);      // lookahead-2 (tail loads clamped, unused)
      v2f Ln, Cn, Rn;
      MK(xC, (r == RSTRIP - 1) ? rv8 : 1.f, Ln, Cn, Rn)
      v2f a = acc[r];
      a = vfma(w00, Lm, a); a = vfma(w01, Cm, a); a = vfma(w02, Rm, a);
      a = vfma(w10, Lc, a); a = vfma(w11, Cc, a); a = vfma(w12, Rc, a);
      a = vfma(w20, Ln, a); a = vfma(w21, Cn, a); a = vfma(w22, Rn, a);
      acc[r] = a;
      Lm = Lc; Cm = Cc; Rm = Rc;
      Lc = Ln; Cc = Cn; Rc = Rn;
      xC = xD; xD = xE;
    }
#undef MK
#undef LDROW
  }

  // reduce the four i-quarters through LDS (lane-major; b64 2-way is free)
  __shared__ v2f red[3][RSTRIP][64];   // 12 KB
  if (iq != 0) {
#pragma unroll
    for (int r = 0; r < RSTRIP; ++r) red[iq - 1][r][lane] = acc[r];
  }
  __syncthreads();
  if (iq == 0) {
    float* yb = y + (((size_t)b * 32 + o) * 128 + r0) * 128 + c0;
#pragma unroll
    for (int r = 0; r < RSTRIP; ++r) {
      const v2f v = acc[r] + red[0][r][lane] + red[1][r][lane] + red[2][r][lane];
      *(v2f*)(yb + (size_t)r * 128) = v;
    }
  }
}

__global__ __launch_bounds__(256) void mix1x1(
    const float* __restrict__ y,    // (B, O, H*W)
    const float* __restrict__ fw,   // (O_out, O_in)
    float* __restrict__ out)        // (B, O, H*W)
{
  const int px = blockIdx.x * 256 + threadIdx.x;  // 0..16383
  const int b  = blockIdx.y;
  const float* yb = y + (size_t)b * 32 * 16384 + px;
  float v[32];
#pragma unroll
  for (int o = 0; o < 32; ++o) v[o] = yb[(size_t)o * 16384];
  float* ob = out + (size_t)b * 32 * 16384 + px;
#pragma unroll
  for (int p = 0; p < 32; ++p) {
    float a = 0.f;
#pragma unroll
    for (int o = 0; o < 32; ++o) a = fmaf(fw[p * 32 + o], v[o], a);
    ob[(size_t)p * 16384] = a;
  }
}

extern "C" void kernel_launch(void* const* d_in, const int* in_sizes, int n_in,
                              void* d_out, int out_size, void* d_ws, size_t ws_size,
                              hipStream_t stream) {
  const float* x     = (const float*)d_in[0];
  const float* scale = (const float*)d_in[1];
  const float* trans = (const float*)d_in[2];
  const float* wconv = (const float*)d_in[3];
  const float* fw    = (const float*)d_in[4];
  float* out = (float*)d_out;
  float* y   = (float*)d_ws;   // 4*32*128*128 floats = 8.39 MB

  const float mhc = (float)(2.0 / (sqrt(3.0) * pow(M_PI, 0.25)));

  dim3 g1(128 / RSTRIP, 32, 4);  // (strips, o, b) = 2048 blocks x 256 thr
  wavelet_grouped_conv<<<g1, 256, 0, stream>>>(x, scale, trans, wconv, y, mhc);

  dim3 g2(16384 / 256, 4);       // (pixel tiles, b)
  mix1x1<<<g2, 256, 0, stream>>>(y, fw, out);
}